// Round 4
// baseline (934.055 us; speedup 1.0000x reference)
//
#include <hip/hip_runtime.h>

#define NS 32768
#define NLEV 4
#define NF 512
#define HID 512
#define VQD 64
#define CBS 4096

typedef __attribute__((ext_vector_type(8))) short bf16x8;
typedef __attribute__((ext_vector_type(4))) float f32x4;

__device__ inline unsigned short f2bf(float f) {
    unsigned int u = __float_as_uint(f);
    unsigned int r = (u + 0x7FFFu + ((u >> 16) & 1u)) >> 16;
    return (unsigned short)r;
}

// async global->LDS, 16B per lane; lds base must be wave-uniform
__device__ __forceinline__ void gl16(const void* g, void* l) {
    __builtin_amdgcn_global_load_lds(
        (const __attribute__((address_space(1))) unsigned int*)g,
        (__attribute__((address_space(3))) unsigned int*)l, 16, 0, 0);
}

// ---------------- prep kernels ----------------

__global__ void transpose_all(const float* __restrict__ ew1, const float* __restrict__ ew2,
                              const float* __restrict__ dw1, const float* __restrict__ dw2,
                              unsigned short* __restrict__ ew1t, unsigned short* __restrict__ ew2t,
                              unsigned short* __restrict__ dw1t, unsigned short* __restrict__ dw2t) {
    long i = (long)blockIdx.x * 256 + threadIdx.x;
    const long s1 = (long)NLEV * NF * HID;
    const long s2 = (long)NLEV * HID * VQD;
    const long s3 = (long)NLEV * VQD * HID;
    const long s4 = (long)NLEV * HID * NF;
    const float* src;
    unsigned short* dst;
    int R, C;
    if (i < s1) { src = ew1; dst = ew1t; R = NF; C = HID; }
    else if (i < s1 + s2) { i -= s1; src = ew2; dst = ew2t; R = HID; C = VQD; }
    else if (i < s1 + s2 + s3) { i -= s1 + s2; src = dw1; dst = dw1t; R = VQD; C = HID; }
    else if (i < s1 + s2 + s3 + s4) { i -= s1 + s2 + s3; src = dw2; dst = dw2t; R = HID; C = NF; }
    else return;
    int r = (int)(i % R);
    long t = i / R;
    int c = (int)(t % C);
    int b = (int)(t / C);
    dst[i] = f2bf(src[((long)b * R + r) * C + c]);
}

__global__ void cb_prep(const float* __restrict__ cb, unsigned short* __restrict__ cbb,
                        float* __restrict__ cbn) {
    int i = blockIdx.x * 256 + threadIdx.x;  // l*CBS + n
    if (i >= NLEV * CBS) return;
    const float* row = cb + (long)i * VQD;
    float s = 0.f;
    for (int k = 0; k < VQD; k++) {
        float v = row[k];
        s += v * v;
        cbb[(long)i * VQD + k] = f2bf(v);
    }
    cbn[i] = s;
}

// all levels: x[n][l][f] fp32 -> xb[l][n][f] bf16
__global__ void xconv(const float* __restrict__ x, unsigned short* __restrict__ xb) {
    long i = (long)blockIdx.x * 256 + threadIdx.x;  // one per 8 elements
    int l = (int)(i / ((long)NS * (NF / 8)));
    long rem = i % ((long)NS * (NF / 8));
    int n = (int)(rem >> 6);
    int f8 = ((int)rem & 63) * 8;
    const float* src = x + ((long)n * NLEV + l) * NF + f8;
    float4 f0 = *(const float4*)src;
    float4 f1 = *(const float4*)(src + 4);
    short t[8];
    t[0] = (short)f2bf(f0.x); t[1] = (short)f2bf(f0.y); t[2] = (short)f2bf(f0.z); t[3] = (short)f2bf(f0.w);
    t[4] = (short)f2bf(f1.x); t[5] = (short)f2bf(f1.y); t[6] = (short)f2bf(f1.z); t[7] = (short)f2bf(f1.w);
    *(int4*)(xb + ((long)l * NS + n) * NF + f8) = *(const int4*)t;
}

// ---------------- 128xBN-tile MFMA GEMM, 1D panel-major grid ----------------
// bid = (lvl*NBPAN + n_blk)*256 + mblk  -> consecutive blocks share the B panel.
// C[m][n] = act( sum_k A[m][k] * Bt[n][k] + bias[n] )
// OUT_MODE: 0 = bf16 C; 1 = f32 C + bf16 C; 2 = fused MSE vs Xref (no C write)
// GATHER: A row = codebook[idx[m]]
template <int NT, int NTOT, int RELU, int OUT_MODE, int GATHER>
__global__ __launch_bounds__(256) void gemm128(
    const unsigned short* __restrict__ Ab, long astride, long abatch,
    const int* __restrict__ idx,
    const unsigned short* __restrict__ Bt, long bbatch,
    const float* __restrict__ bias, long biasbatch,
    unsigned short* __restrict__ Cb, float* __restrict__ Cf, long cbatch,
    const float* __restrict__ Xref, long xstride, long xbatch,
    float* __restrict__ accum, int K) {
    constexpr int BN = NT * 32;
    constexpr int NBPAN = NTOT / BN;
    constexpr int BNP = BN + 8;  // padded repack stride
    constexpr int SMEM = (128 * 32 + BN * 32) > (64 * BNP) ? (128 * 32 + BN * 32) : (64 * BNP);
    __shared__ __align__(16) short smem[SMEM];
    short* As = smem;
    short* Bs = smem + 128 * 32;
    __shared__ float red[4];

    const int bid = blockIdx.x;
    const int mblk = bid & 255;
    const int panel = bid >> 8;
    const int n_blk = panel % NBPAN;
    const int lvl = panel / NBPAN;

    Ab += (long)lvl * abatch;
    Bt += (long)lvl * bbatch;
    bias += (long)lvl * biasbatch;
    if (OUT_MODE == 0 || OUT_MODE == 1) Cb += (long)lvl * cbatch;
    if (OUT_MODE == 1) Cf += (long)lvl * cbatch;
    if (OUT_MODE == 2) Xref += (long)lvl * xbatch;
    if (GATHER) idx += (long)lvl * NS;

    const int tid = threadIdx.x;
    const int m0 = mblk * 128;
    const int n0 = n_blk * BN;
    const int wave = tid >> 6, lane = tid & 63, quad = lane >> 4, lr = lane & 15;
    const int wm = wave >> 1, wn = wave & 1;
    const int lrow = lane >> 2;       // 0..15
    const int lcol = (lane & 3) * 8;  // 0,8,16,24

    f32x4 acc[4][NT];
#pragma unroll
    for (int i = 0; i < 4; i++)
#pragma unroll
        for (int j = 0; j < NT; j++) acc[i][j] = (f32x4){0.f, 0.f, 0.f, 0.f};

    for (int k0 = 0; k0 < K; k0 += 32) {
        if (GATHER) {
            int r0 = m0 + wave * 16 + lrow;
            gl16(Ab + (long)idx[r0] * K + k0 + lcol, &As[(wave * 16) * 32]);
            gl16(Ab + (long)idx[r0 + 64] * K + k0 + lcol, &As[(64 + wave * 16) * 32]);
        } else {
            const unsigned short* ga = Ab + (long)(m0 + wave * 16 + lrow) * astride + k0 + lcol;
            gl16(ga, &As[(wave * 16) * 32]);
            gl16(ga + 64 * astride, &As[(64 + wave * 16) * 32]);
        }
        const unsigned short* gb = Bt + (long)(n0 + wave * 16 + lrow) * K + k0 + lcol;
        gl16(gb, &Bs[(wave * 16) * 32]);
        if (NT == 4) gl16(gb + 64 * (long)K, &Bs[(64 + wave * 16) * 32]);
        __syncthreads();

        bf16x8 af[4], bfr[NT];
#pragma unroll
        for (int mt = 0; mt < 4; mt++)
            af[mt] = *(const bf16x8*)&As[(wm * 64 + mt * 16 + lr) * 32 + quad * 8];
#pragma unroll
        for (int nt = 0; nt < NT; nt++)
            bfr[nt] = *(const bf16x8*)&Bs[(wn * NT * 16 + nt * 16 + lr) * 32 + quad * 8];
#pragma unroll
        for (int mt = 0; mt < 4; mt++)
#pragma unroll
            for (int nt = 0; nt < NT; nt++)
                acc[mt][nt] = __builtin_amdgcn_mfma_f32_16x16x32_bf16(af[mt], bfr[nt], acc[mt][nt], 0, 0, 0);
        __syncthreads();
    }

    // cache bias for this lane's columns
    float bvs[NT];
#pragma unroll
    for (int nt = 0; nt < NT; nt++) bvs[nt] = bias[n0 + wn * NT * 16 + nt * 16 + lr];

    if (OUT_MODE == 2) {
        float lsum = 0.f;
#pragma unroll
        for (int nt = 0; nt < NT; nt++) {
            int col = n0 + wn * NT * 16 + nt * 16 + lr;
#pragma unroll
            for (int mt = 0; mt < 4; mt++) {
#pragma unroll
                for (int r = 0; r < 4; r++) {
                    int row = m0 + wm * 64 + mt * 16 + quad * 4 + r;
                    float v = acc[mt][nt][r] + bvs[nt];
                    float d = v - Xref[(long)row * xstride + col];
                    lsum += d * d;
                }
            }
        }
#pragma unroll
        for (int off = 32; off; off >>= 1) lsum += __shfl_down(lsum, off, 64);
        if (lane == 0) red[wave] = lsum;
        __syncthreads();
        if (tid == 0) atomicAdd(accum, red[0] + red[1] + red[2] + red[3]);
    } else {
        // two-phase LDS repack -> coalesced 16B stores
        short* Ct = smem;  // 64 x BNP
#pragma unroll
        for (int p = 0; p < 2; p++) {
            __syncthreads();
            if (wm == p) {
#pragma unroll
                for (int nt = 0; nt < NT; nt++) {
                    int cl = wn * NT * 16 + nt * 16 + lr;
#pragma unroll
                    for (int mt = 0; mt < 4; mt++) {
#pragma unroll
                        for (int r = 0; r < 4; r++) {
                            int rl = mt * 16 + quad * 4 + r;
                            float v = acc[mt][nt][r] + bvs[nt];
                            if (RELU) v = v > 0.f ? v : 0.f;
                            Ct[rl * BNP + cl] = (short)f2bf(v);
                        }
                    }
                }
            }
            __syncthreads();
            constexpr int PER = (64 * BN / 8) / 256;  // int4 chunks per thread (4 or 2)
#pragma unroll
            for (int j = 0; j < PER; j++) {
                int id = j * 256 + tid;
                int row = id / (BN / 8);
                int seg = id % (BN / 8);
                int4 raw;
                short tmp[8];
                *(int4*)tmp = *(const int4*)&Ct[row * BNP + seg * 8];
                raw = *(const int4*)tmp;
                int rg = m0 + p * 64 + row;
                int cg = n0 + seg * 8;
                *(int4*)&Cb[(long)rg * NTOT + cg] = raw;
                if (OUT_MODE == 1) {
                    float f[8];
#pragma unroll
                    for (int e = 0; e < 8; e++)
                        f[e] = __uint_as_float(((unsigned int)(unsigned short)tmp[e]) << 16);
                    *(float4*)&Cf[(long)rg * NTOT + cg] = (float4){f[0], f[1], f[2], f[3]};
                    *(float4*)&Cf[(long)rg * NTOT + cg + 4] = (float4){f[4], f[5], f[6], f[7]};
                }
            }
        }
    }
}

// ---------------- VQ distance + argmin, 128-row tile, level-batched ----------------
__global__ __launch_bounds__(256) void vq_argmin(const unsigned short* __restrict__ Zb,
                                                 const unsigned short* __restrict__ cbb,
                                                 const float* __restrict__ cbn,
                                                 int* __restrict__ idxo) {
    __shared__ __align__(16) short Zs[2 * 128 * 32];
    __shared__ __align__(16) short Cs[2 * 64 * 32];
    const int lvl = blockIdx.y;
    Zb += (long)lvl * NS * VQD;
    cbb += (long)lvl * CBS * VQD;
    cbn += (long)lvl * CBS;
    idxo += (long)lvl * NS;
    const int tid = threadIdx.x;
    const int m0 = blockIdx.x * 128;
    const int wave = tid >> 6, lane = tid & 63, quad = lane >> 4, lr = lane & 15;
    const int lrow = lane >> 2, lcol = (lane & 3) * 8;

#pragma unroll
    for (int j = 0; j < 4; j++) {
        int f = tid * 4 + j;  // int4 index, 0..1023
        int p = f >> 9;
        int rem = f & 511;
        int r = rem >> 2;
        int c = (rem & 3) * 8;
        ((int4*)Zs)[f] = *(const int4*)(Zb + (long)(m0 + r) * VQD + p * 32 + c);
    }
    __syncthreads();
    bf16x8 a[2][2];
#pragma unroll
    for (int h = 0; h < 2; h++)
#pragma unroll
        for (int p = 0; p < 2; p++)
            a[h][p] = *(const bf16x8*)&Zs[p * 4096 + (h * 64 + wave * 16 + lr) * 32 + quad * 8];

    float minv[2][4] = {{1e30f, 1e30f, 1e30f, 1e30f}, {1e30f, 1e30f, 1e30f, 1e30f}};
    int mini[2][4] = {{0, 0, 0, 0}, {0, 0, 0, 0}};

    for (int nb = 0; nb < CBS; nb += 64) {
        __syncthreads();
#pragma unroll
        for (int i = 0; i < 2; i++) {
            int s = i * 4 + wave;  // segment 0..7
            int p = s >> 2;
            int r0 = (s & 3) * 16;
            gl16(cbb + (long)(nb + r0 + lrow) * VQD + p * 32 + lcol, &Cs[s * 512]);
        }
        __syncthreads();
#pragma unroll
        for (int nt = 0; nt < 4; nt++) {
            bf16x8 b0 = *(const bf16x8*)&Cs[(nt * 16 + lr) * 32 + quad * 8];
            bf16x8 b1 = *(const bf16x8*)&Cs[2048 + (nt * 16 + lr) * 32 + quad * 8];
            int n = nb + nt * 16 + lr;
            float cn = cbn[n];
#pragma unroll
            for (int h = 0; h < 2; h++) {
                f32x4 acc = {0.f, 0.f, 0.f, 0.f};
                acc = __builtin_amdgcn_mfma_f32_16x16x32_bf16(a[h][0], b0, acc, 0, 0, 0);
                acc = __builtin_amdgcn_mfma_f32_16x16x32_bf16(a[h][1], b1, acc, 0, 0, 0);
#pragma unroll
                for (int r = 0; r < 4; r++) {
                    float d = cn - 2.0f * acc[r];
                    if (d < minv[h][r]) {
                        minv[h][r] = d;
                        mini[h][r] = n;
                    }
                }
            }
        }
    }
#pragma unroll
    for (int h = 0; h < 2; h++)
#pragma unroll
        for (int r = 0; r < 4; r++) {
            float v = minv[h][r];
            int ix = mini[h][r];
#pragma unroll
            for (int off = 8; off; off >>= 1) {
                float ov = __shfl_xor(v, off, 64);
                int oi = __shfl_xor(ix, off, 64);
                if (ov < v || (ov == v && oi < ix)) {
                    v = ov;
                    ix = oi;
                }
            }
            if (lr == 0) idxo[m0 + h * 64 + wave * 16 + quad * 4 + r] = ix;
        }
}

// ---------------- commit SSE (last level only) ----------------
__global__ __launch_bounds__(256) void commit_k(const int* __restrict__ idx,
                                                const float* __restrict__ cbf,
                                                const float* __restrict__ zf,
                                                float* __restrict__ accum) {
    int m = blockIdx.x * 256 + threadIdx.x;
    int id = idx[m];
    const float* c = cbf + (long)id * VQD;
    const float* z = zf + (long)m * VQD;
    float s = 0.f;
#pragma unroll
    for (int k = 0; k < VQD; k++) {
        float d = c[k] - z[k];
        s += d * d;
    }
    int lane = threadIdx.x & 63;
#pragma unroll
    for (int off = 32; off; off >>= 1) s += __shfl_down(s, off, 64);
    if (lane == 0) atomicAdd(accum, s);
}

__global__ void finalize_k(const float* __restrict__ accum, float* __restrict__ out) {
    out[0] = accum[0] / ((float)NS * NF * NLEV);
    out[1] = 0.25f * accum[1] / ((float)NS * VQD * NLEV);
}

// ---------------- launch ----------------
extern "C" void kernel_launch(void* const* d_in, const int* in_sizes, int n_in, void* d_out,
                              int out_size, void* d_ws, size_t ws_size, hipStream_t stream) {
    const float* x = (const float*)d_in[0];
    const float* enc_w1 = (const float*)d_in[1];
    const float* enc_b1 = (const float*)d_in[2];
    const float* enc_w2 = (const float*)d_in[3];
    const float* enc_b2 = (const float*)d_in[4];
    const float* dec_w1 = (const float*)d_in[5];
    const float* dec_b1 = (const float*)d_in[6];
    const float* dec_w2 = (const float*)d_in[7];
    const float* dec_b2 = (const float*)d_in[8];
    const float* cb = (const float*)d_in[9];

    char* ws = (char*)d_ws;
    size_t o = 0;
    float* accum = (float*)(ws + o); o += 256;
    unsigned short* enc_w1t = (unsigned short*)(ws + o); o += (size_t)NLEV * HID * NF * 2;  // [l][n][k]
    unsigned short* enc_w2t = (unsigned short*)(ws + o); o += (size_t)NLEV * VQD * HID * 2;
    unsigned short* dec_w1t = (unsigned short*)(ws + o); o += (size_t)NLEV * HID * VQD * 2;
    unsigned short* dec_w2t = (unsigned short*)(ws + o); o += (size_t)NLEV * NF * HID * 2;
    unsigned short* cbb = (unsigned short*)(ws + o); o += (size_t)NLEV * CBS * VQD * 2;
    float* cbn = (float*)(ws + o); o += (size_t)NLEV * CBS * 4;
    unsigned short* xb = (unsigned short*)(ws + o); o += (size_t)NLEV * NS * NF * 2;  // 128 MB; reused as h2b
    unsigned short* hb = (unsigned short*)(ws + o); o += (size_t)NLEV * NS * HID * 2; // 128 MB
    float* zf = (float*)(ws + o); o += (size_t)NLEV * NS * VQD * 4;                   // 32 MB
    unsigned short* zb = (unsigned short*)(ws + o); o += (size_t)NLEV * NS * VQD * 2; // 16 MB
    int* idxp = (int*)(ws + o); o += (size_t)NLEV * NS * 4;
    unsigned short* h2b = xb;  // alias: xb dead after batched enc1

    hipMemsetAsync(accum, 0, 8, stream);

    transpose_all<<<(2 * NLEV * NF * HID + 2 * NLEV * HID * VQD + 255) / 256, 256, 0, stream>>>(
        enc_w1, enc_w2, dec_w1, dec_w2, enc_w1t, enc_w2t, dec_w1t, dec_w2t);
    cb_prep<<<(NLEV * CBS + 255) / 256, 256, 0, stream>>>(cb, cbb, cbn);
    xconv<<<(int)(((long)NLEV * NS * (NF / 8) + 255) / 256), 256, 0, stream>>>(x, xb);

    const int gBig = 256 * (HID / 128) * NLEV;  // 4096, panel-major 1D
    const int gZ = 256 * 1 * NLEV;              // 1024
    dim3 gVQ(NS / 128, NLEV);

    // enc1: h = relu(xb @ enc_w1 + b1)
    gemm128<4, HID, 1, 0, 0><<<gBig, 256, 0, stream>>>(
        xb, NF, (long)NS * NF, nullptr,
        enc_w1t, (long)HID * NF, enc_b1, HID,
        hb, nullptr, (long)NS * HID, nullptr, 0, 0, nullptr, NF);
    // enc2: z = h @ enc_w2 + b2  (bf16 + f32 z; f32 used by commit on last level)
    gemm128<2, VQD, 0, 1, 0><<<gZ, 256, 0, stream>>>(
        hb, HID, (long)NS * HID, nullptr,
        enc_w2t, (long)VQD * HID, enc_b2, VQD,
        zb, zf, (long)NS * VQD, nullptr, 0, 0, nullptr, HID);
    // argmin over codebook
    vq_argmin<<<gVQ, 256, 0, stream>>>(zb, cbb, cbn, idxp);
    // commit SSE, last level only
    commit_k<<<NS / 256, 256, 0, stream>>>(idxp + (long)(NLEV - 1) * NS,
                                           cb + (long)(NLEV - 1) * CBS * VQD,
                                           zf + (long)(NLEV - 1) * NS * VQD, accum + 1);
    // dec1: h2 = relu(cb[idx] @ dec_w1 + b1d), gather fused into A staging
    gemm128<4, HID, 1, 0, 1><<<gBig, 256, 0, stream>>>(
        cbb, 0, (long)CBS * VQD, idxp,
        dec_w1t, (long)HID * VQD, dec_b1, HID,
        h2b, nullptr, (long)NS * HID, nullptr, 0, 0, nullptr, VQD);
    // dec2 + fused MSE: x_hat = h2 @ dec_w2 + b2d; accumulate sum((x_hat - x_l)^2)
    gemm128<4, NF, 0, 2, 0><<<gBig, 256, 0, stream>>>(
        h2b, HID, (long)NS * HID, nullptr,
        dec_w2t, (long)NF * HID, dec_b2, NF,
        nullptr, nullptr, 0, x, (long)NLEV * NF, NF, accum, HID);

    finalize_k<<<1, 1, 0, stream>>>(accum, (float*)d_out);
}

// Round 5
// 838.838 us; speedup vs baseline: 1.1135x; 1.1135x over previous
//
#include <hip/hip_runtime.h>

#define NS 32768
#define NLEV 4
#define NF 512
#define HID 512
#define VQD 64
#define CBS 4096

typedef __attribute__((ext_vector_type(8))) short bf16x8;
typedef __attribute__((ext_vector_type(4))) float f32x4;

__device__ inline unsigned short f2bf(float f) {
    unsigned int u = __float_as_uint(f);
    unsigned int r = (u + 0x7FFFu + ((u >> 16) & 1u)) >> 16;
    return (unsigned short)r;
}
__device__ inline float bf2f(unsigned short s) {
    return __uint_as_float(((unsigned int)s) << 16);
}

// async global->LDS, 16B per lane; lds base must be wave-uniform
__device__ __forceinline__ void gl16(const void* g, void* l) {
    __builtin_amdgcn_global_load_lds(
        (const __attribute__((address_space(1))) unsigned int*)g,
        (__attribute__((address_space(3))) unsigned int*)l, 16, 0, 0);
}

// ---------------- prep kernels ----------------

__global__ void transpose_all(const float* __restrict__ ew1, const float* __restrict__ ew2,
                              const float* __restrict__ dw1, const float* __restrict__ dw2,
                              unsigned short* __restrict__ ew1t, unsigned short* __restrict__ ew2t,
                              unsigned short* __restrict__ dw1t, unsigned short* __restrict__ dw2t) {
    long i = (long)blockIdx.x * 256 + threadIdx.x;
    const long s1 = (long)NLEV * NF * HID;
    const long s2 = (long)NLEV * HID * VQD;
    const long s3 = (long)NLEV * VQD * HID;
    const long s4 = (long)NLEV * HID * NF;
    const float* src;
    unsigned short* dst;
    int R, C;
    if (i < s1) { src = ew1; dst = ew1t; R = NF; C = HID; }
    else if (i < s1 + s2) { i -= s1; src = ew2; dst = ew2t; R = HID; C = VQD; }
    else if (i < s1 + s2 + s3) { i -= s1 + s2; src = dw1; dst = dw1t; R = VQD; C = HID; }
    else if (i < s1 + s2 + s3 + s4) { i -= s1 + s2 + s3; src = dw2; dst = dw2t; R = HID; C = NF; }
    else return;
    int r = (int)(i % R);
    long t = i / R;
    int c = (int)(t % C);
    int b = (int)(t / C);
    dst[i] = f2bf(src[((long)b * R + r) * C + c]);
}

__global__ void cb_prep(const float* __restrict__ cb, unsigned short* __restrict__ cbb,
                        float* __restrict__ cbn) {
    int i = blockIdx.x * 256 + threadIdx.x;  // l*CBS + n
    if (i >= NLEV * CBS) return;
    const float* row = cb + (long)i * VQD;
    float s = 0.f;
    for (int k = 0; k < VQD; k++) {
        float v = row[k];
        s += v * v;
        cbb[(long)i * VQD + k] = f2bf(v);
    }
    cbn[i] = s;
}

// all levels: x[n][l][f] fp32 -> xb[l][n][f] bf16
__global__ void xconv(const float* __restrict__ x, unsigned short* __restrict__ xb) {
    long i = (long)blockIdx.x * 256 + threadIdx.x;  // one per 8 elements
    int l = (int)(i / ((long)NS * (NF / 8)));
    long rem = i % ((long)NS * (NF / 8));
    int n = (int)(rem >> 6);
    int f8 = ((int)rem & 63) * 8;
    const float* src = x + ((long)n * NLEV + l) * NF + f8;
    float4 f0 = *(const float4*)src;
    float4 f1 = *(const float4*)(src + 4);
    short t[8];
    t[0] = (short)f2bf(f0.x); t[1] = (short)f2bf(f0.y); t[2] = (short)f2bf(f0.z); t[3] = (short)f2bf(f0.w);
    t[4] = (short)f2bf(f1.x); t[5] = (short)f2bf(f1.y); t[6] = (short)f2bf(f1.z); t[7] = (short)f2bf(f1.w);
    *(int4*)(xb + ((long)l * NS + n) * NF + f8) = *(const int4*)t;
}

// ---------------- 128xBN-tile MFMA GEMM, BK=64 (two LDS panels per barrier-pair) ----
// 1D grid, chunk swizzle: 32-block chunk = 8 mblks x NPAN panels (A L2 reuse).
// OUT_MODE: 0 = bf16 C; 2 = fused MSE vs bf16 Xref (no C write)
// GATHER: A row = codebook[idx[m]]
template <int NT, int NTOT, int RELU, int OUT_MODE, int GATHER>
__global__ __launch_bounds__(256) void gemm128(
    const unsigned short* __restrict__ Ab, long astride, long abatch,
    const int* __restrict__ idx,
    const unsigned short* __restrict__ Bt, long bbatch,
    const float* __restrict__ bias, long biasbatch,
    unsigned short* __restrict__ Cb, long cbatch,
    const unsigned short* __restrict__ Xref, long xbatch,
    float* __restrict__ accum, int K) {
    constexpr int BN = NT * 32;
    constexpr int NPAN = NTOT / BN;
    constexpr int BNP = BN + 8;  // padded repack stride
    __shared__ __align__(16) short smem[2 * 128 * 32 + 2 * BN * 32];
    short* As = smem;                   // panel p at p*4096
    short* Bs = smem + 2 * 128 * 32;    // panel p at p*BN*32
    __shared__ float red[4];

    const int bid = blockIdx.x;
    const int inner = bid % (256 * NPAN);
    const int lvl = bid / (256 * NPAN);
    constexpr int CHUNK = 8 * NPAN;
    const int mblk = (inner / CHUNK) * 8 + (inner % CHUNK) / NPAN;
    const int n_blk = inner % NPAN;

    Ab += (long)lvl * abatch;
    Bt += (long)lvl * bbatch;
    bias += (long)lvl * biasbatch;
    if (OUT_MODE == 0) Cb += (long)lvl * cbatch;
    if (OUT_MODE == 2) Xref += (long)lvl * xbatch;
    if (GATHER) idx += (long)lvl * NS;

    const int tid = threadIdx.x;
    const int m0 = mblk * 128;
    const int n0 = n_blk * BN;
    const int wave = tid >> 6, lane = tid & 63, quad = lane >> 4, lr = lane & 15;
    const int wm = wave >> 1, wn = wave & 1;
    const int lrow = lane >> 2;       // 0..15
    const int lcol = (lane & 3) * 8;  // 0,8,16,24

    long idx0 = 0, idx1 = 0;
    if (GATHER) {
        idx0 = idx[m0 + wave * 16 + lrow];
        idx1 = idx[m0 + 64 + wave * 16 + lrow];
    }

    f32x4 acc[4][NT];
#pragma unroll
    for (int i = 0; i < 4; i++)
#pragma unroll
        for (int j = 0; j < NT; j++) acc[i][j] = (f32x4){0.f, 0.f, 0.f, 0.f};

    for (int k0 = 0; k0 < K; k0 += 64) {
#pragma unroll
        for (int p = 0; p < 2; p++) {
            const int kk = k0 + p * 32;
            if (GATHER) {
                gl16(Ab + idx0 * K + kk + lcol, &As[p * 4096 + (wave * 16) * 32]);
                gl16(Ab + idx1 * K + kk + lcol, &As[p * 4096 + (64 + wave * 16) * 32]);
            } else {
                const unsigned short* ga = Ab + (long)(m0 + wave * 16 + lrow) * astride + kk + lcol;
                gl16(ga, &As[p * 4096 + (wave * 16) * 32]);
                gl16(ga + 64 * astride, &As[p * 4096 + (64 + wave * 16) * 32]);
            }
            const unsigned short* gb = Bt + (long)(n0 + wave * 16 + lrow) * K + kk + lcol;
            gl16(gb, &Bs[p * BN * 32 + (wave * 16) * 32]);
            if (NT == 4) gl16(gb + 64 * (long)K, &Bs[p * BN * 32 + (64 + wave * 16) * 32]);
        }
        __syncthreads();
#pragma unroll
        for (int p = 0; p < 2; p++) {
            bf16x8 af[4], bfr[NT];
#pragma unroll
            for (int mt = 0; mt < 4; mt++)
                af[mt] = *(const bf16x8*)&As[p * 4096 + (wm * 64 + mt * 16 + lr) * 32 + quad * 8];
#pragma unroll
            for (int nt = 0; nt < NT; nt++)
                bfr[nt] = *(const bf16x8*)&Bs[p * BN * 32 + (wn * NT * 16 + nt * 16 + lr) * 32 + quad * 8];
#pragma unroll
            for (int mt = 0; mt < 4; mt++)
#pragma unroll
                for (int nt = 0; nt < NT; nt++)
                    acc[mt][nt] = __builtin_amdgcn_mfma_f32_16x16x32_bf16(af[mt], bfr[nt], acc[mt][nt], 0, 0, 0);
        }
        __syncthreads();
    }

    float bvs[NT];
#pragma unroll
    for (int nt = 0; nt < NT; nt++) bvs[nt] = bias[n0 + wn * NT * 16 + nt * 16 + lr];

    if (OUT_MODE == 2) {
        float lsum = 0.f;
#pragma unroll
        for (int nt = 0; nt < NT; nt++) {
            int col = n0 + wn * NT * 16 + nt * 16 + lr;
#pragma unroll
            for (int mt = 0; mt < 4; mt++) {
#pragma unroll
                for (int r = 0; r < 4; r++) {
                    int row = m0 + wm * 64 + mt * 16 + quad * 4 + r;
                    float v = acc[mt][nt][r] + bvs[nt];
                    float d = v - bf2f(Xref[(long)row * NTOT + col]);
                    lsum += d * d;
                }
            }
        }
#pragma unroll
        for (int off = 32; off; off >>= 1) lsum += __shfl_down(lsum, off, 64);
        if (lane == 0) red[wave] = lsum;
        __syncthreads();
        if (tid == 0) atomicAdd(accum, red[0] + red[1] + red[2] + red[3]);
    } else {
        // two-phase LDS repack -> coalesced 16B stores
        short* Ct = smem;  // 64 x BNP overlay
#pragma unroll
        for (int p = 0; p < 2; p++) {
            __syncthreads();
            if (wm == p) {
#pragma unroll
                for (int nt = 0; nt < NT; nt++) {
                    int cl = wn * NT * 16 + nt * 16 + lr;
#pragma unroll
                    for (int mt = 0; mt < 4; mt++) {
#pragma unroll
                        for (int r = 0; r < 4; r++) {
                            int rl = mt * 16 + quad * 4 + r;
                            float v = acc[mt][nt][r] + bvs[nt];
                            if (RELU) v = v > 0.f ? v : 0.f;
                            Ct[rl * BNP + cl] = (short)f2bf(v);
                        }
                    }
                }
            }
            __syncthreads();
            constexpr int PER = (64 * BN / 8) / 256;
#pragma unroll
            for (int j = 0; j < PER; j++) {
                int id = j * 256 + tid;
                int row = id / (BN / 8);
                int seg = id % (BN / 8);
                short tmp[8];
                *(int4*)tmp = *(const int4*)&Ct[row * BNP + seg * 8];
                *(int4*)&Cb[(long)(m0 + p * 64 + row) * NTOT + n0 + seg * 8] = *(const int4*)tmp;
            }
        }
    }
}

// ---------------- fused enc2 + VQ argmin + commit ----------------
// z = hb_tile @ ew2t + b2 (K=512, 128x64 tile) -> LDS -> argmin over codebook
// commit (last level): sum(d_min + ||z||^2), d_min = ||c||^2 - 2 z.c
__global__ __launch_bounds__(256) void enc2_vq(
    const unsigned short* __restrict__ hb, const unsigned short* __restrict__ ew2t,
    const float* __restrict__ eb2, const unsigned short* __restrict__ cbb,
    const float* __restrict__ cbn, int* __restrict__ idxo, float* __restrict__ accum) {
    __shared__ __align__(16) short As[2 * 128 * 32];  // GEMM A panels; then Zs
    __shared__ __align__(16) short Bs[2 * 64 * 32];   // GEMM B panels; then Cs
    __shared__ float znp[2][128];
    __shared__ float zn2[128];
    __shared__ float cred;

    const int lvl = blockIdx.y;
    hb += (long)lvl * NS * HID;
    ew2t += (long)lvl * VQD * HID;
    eb2 += (long)lvl * VQD;
    cbb += (long)lvl * CBS * VQD;
    cbn += (long)lvl * CBS;
    idxo += (long)lvl * NS;

    const int tid = threadIdx.x;
    const int m0 = blockIdx.x * 128;
    const int wave = tid >> 6, lane = tid & 63, quad = lane >> 4, lr = lane & 15;
    const int wm = wave >> 1, wn = wave & 1;
    const int lrow = lane >> 2, lcol = (lane & 3) * 8;

    if (tid == 0) cred = 0.f;

    // ---- GEMM: z[128][64], NT=2 ----
    f32x4 acc[4][2];
#pragma unroll
    for (int i = 0; i < 4; i++)
#pragma unroll
        for (int j = 0; j < 2; j++) acc[i][j] = (f32x4){0.f, 0.f, 0.f, 0.f};

    for (int k0 = 0; k0 < HID; k0 += 64) {
#pragma unroll
        for (int p = 0; p < 2; p++) {
            const int kk = k0 + p * 32;
            const unsigned short* ga = hb + (long)(m0 + wave * 16 + lrow) * HID + kk + lcol;
            gl16(ga, &As[p * 4096 + (wave * 16) * 32]);
            gl16(ga + 64 * HID, &As[p * 4096 + (64 + wave * 16) * 32]);
            const unsigned short* gb = ew2t + (long)(wave * 16 + lrow) * HID + kk + lcol;
            gl16(gb, &Bs[p * 2048 + (wave * 16) * 32]);
        }
        __syncthreads();
#pragma unroll
        for (int p = 0; p < 2; p++) {
            bf16x8 af[4], bfr[2];
#pragma unroll
            for (int mt = 0; mt < 4; mt++)
                af[mt] = *(const bf16x8*)&As[p * 4096 + (wm * 64 + mt * 16 + lr) * 32 + quad * 8];
#pragma unroll
            for (int nt = 0; nt < 2; nt++)
                bfr[nt] = *(const bf16x8*)&Bs[p * 2048 + (wn * 32 + nt * 16 + lr) * 32 + quad * 8];
#pragma unroll
            for (int mt = 0; mt < 4; mt++)
#pragma unroll
                for (int nt = 0; nt < 2; nt++)
                    acc[mt][nt] = __builtin_amdgcn_mfma_f32_16x16x32_bf16(af[mt], bfr[nt], acc[mt][nt], 0, 0, 0);
        }
        __syncthreads();
    }

    // ---- z -> Zs (bf16, vq panel layout [2][128][32]), overlay on As ----
    short* Zs = As;
    float bvs[2] = {eb2[wn * 32 + lr], eb2[wn * 32 + 16 + lr]};
#pragma unroll
    for (int mt = 0; mt < 4; mt++)
#pragma unroll
        for (int r = 0; r < 4; r++) {
            int row = wm * 64 + mt * 16 + quad * 4 + r;
#pragma unroll
            for (int nt = 0; nt < 2; nt++) {
                float v = acc[mt][nt][r] + bvs[nt];
                Zs[wn * 4096 + row * 32 + nt * 16 + lr] = (short)f2bf(v);
            }
        }
    __syncthreads();

    // ||z||^2 per row (from bf16 z, fp32 accumulate)
    {
        int row = tid >> 1, p = tid & 1;
        const short* zr = &Zs[p * 4096 + row * 32];
        float s = 0.f;
#pragma unroll
        for (int j = 0; j < 32; j++) {
            float f = bf2f((unsigned short)zr[j]);
            s += f * f;
        }
        znp[p][row] = s;
    }
    bf16x8 a[2][2];
#pragma unroll
    for (int h = 0; h < 2; h++)
#pragma unroll
        for (int p = 0; p < 2; p++)
            a[h][p] = *(const bf16x8*)&Zs[p * 4096 + (h * 64 + wave * 16 + lr) * 32 + quad * 8];
    __syncthreads();
    if (tid < 128) zn2[tid] = znp[0][tid] + znp[1][tid];

    // ---- VQ argmin ----
    short* Cs = Bs;
    float minv[2][4] = {{1e30f, 1e30f, 1e30f, 1e30f}, {1e30f, 1e30f, 1e30f, 1e30f}};
    int mini[2][4] = {{0, 0, 0, 0}, {0, 0, 0, 0}};

    for (int nb = 0; nb < CBS; nb += 64) {
        __syncthreads();
#pragma unroll
        for (int i = 0; i < 2; i++) {
            int s = i * 4 + wave;  // segment 0..7
            int p = s >> 2;
            int r0 = (s & 3) * 16;
            gl16(cbb + (long)(nb + r0 + lrow) * VQD + p * 32 + lcol, &Cs[s * 512]);
        }
        __syncthreads();
#pragma unroll
        for (int nt = 0; nt < 4; nt++) {
            bf16x8 b0 = *(const bf16x8*)&Cs[(nt * 16 + lr) * 32 + quad * 8];
            bf16x8 b1 = *(const bf16x8*)&Cs[2048 + (nt * 16 + lr) * 32 + quad * 8];
            int n = nb + nt * 16 + lr;
            float cn = cbn[n];
#pragma unroll
            for (int h = 0; h < 2; h++) {
                f32x4 d4 = {0.f, 0.f, 0.f, 0.f};
                d4 = __builtin_amdgcn_mfma_f32_16x16x32_bf16(a[h][0], b0, d4, 0, 0, 0);
                d4 = __builtin_amdgcn_mfma_f32_16x16x32_bf16(a[h][1], b1, d4, 0, 0, 0);
#pragma unroll
                for (int r = 0; r < 4; r++) {
                    float d = cn - 2.0f * d4[r];
                    if (d < minv[h][r]) {
                        minv[h][r] = d;
                        mini[h][r] = n;
                    }
                }
            }
        }
    }

    // ---- reduce, write idx, commit ----
    float csum = 0.f;
#pragma unroll
    for (int h = 0; h < 2; h++)
#pragma unroll
        for (int r = 0; r < 4; r++) {
            float v = minv[h][r];
            int ix = mini[h][r];
#pragma unroll
            for (int off = 8; off; off >>= 1) {
                float ov = __shfl_xor(v, off, 64);
                int oi = __shfl_xor(ix, off, 64);
                if (ov < v || (ov == v && oi < ix)) {
                    v = ov;
                    ix = oi;
                }
            }
            if (lr == 0) {
                int row = h * 64 + wave * 16 + quad * 4 + r;
                idxo[m0 + row] = ix;
                csum += v + zn2[row];
            }
        }
    if (lvl == NLEV - 1) {
        if (lr == 0) atomicAdd(&cred, csum);
        __syncthreads();
        if (tid == 0) atomicAdd(accum + 1, cred);
    }
}

__global__ void finalize_k(const float* __restrict__ accum, float* __restrict__ out) {
    out[0] = accum[0] / ((float)NS * NF * NLEV);
    out[1] = 0.25f * accum[1] / ((float)NS * VQD * NLEV);
}

// ---------------- launch ----------------
extern "C" void kernel_launch(void* const* d_in, const int* in_sizes, int n_in, void* d_out,
                              int out_size, void* d_ws, size_t ws_size, hipStream_t stream) {
    const float* x = (const float*)d_in[0];
    const float* enc_w1 = (const float*)d_in[1];
    const float* enc_b1 = (const float*)d_in[2];
    const float* enc_w2 = (const float*)d_in[3];
    const float* enc_b2 = (const float*)d_in[4];
    const float* dec_w1 = (const float*)d_in[5];
    const float* dec_b1 = (const float*)d_in[6];
    const float* dec_w2 = (const float*)d_in[7];
    const float* dec_b2 = (const float*)d_in[8];
    const float* cb = (const float*)d_in[9];

    char* ws = (char*)d_ws;
    size_t o = 0;
    float* accum = (float*)(ws + o); o += 256;
    unsigned short* enc_w1t = (unsigned short*)(ws + o); o += (size_t)NLEV * HID * NF * 2;
    unsigned short* enc_w2t = (unsigned short*)(ws + o); o += (size_t)NLEV * VQD * HID * 2;
    unsigned short* dec_w1t = (unsigned short*)(ws + o); o += (size_t)NLEV * HID * VQD * 2;
    unsigned short* dec_w2t = (unsigned short*)(ws + o); o += (size_t)NLEV * NF * HID * 2;
    unsigned short* cbb = (unsigned short*)(ws + o); o += (size_t)NLEV * CBS * VQD * 2;
    float* cbn = (float*)(ws + o); o += (size_t)NLEV * CBS * 4;
    unsigned short* xb = (unsigned short*)(ws + o); o += (size_t)NLEV * NS * NF * 2;   // 134 MB, live whole call
    unsigned short* hb = (unsigned short*)(ws + o); o += (size_t)NLEV * NS * HID * 2;  // 134 MB, h then h2
    int* idxp = (int*)(ws + o); o += (size_t)NLEV * NS * 4;

    hipMemsetAsync(accum, 0, 8, stream);

    transpose_all<<<(2 * NLEV * NF * HID + 2 * NLEV * HID * VQD + 255) / 256, 256, 0, stream>>>(
        enc_w1, enc_w2, dec_w1, dec_w2, enc_w1t, enc_w2t, dec_w1t, dec_w2t);
    cb_prep<<<(NLEV * CBS + 255) / 256, 256, 0, stream>>>(cb, cbb, cbn);
    xconv<<<(int)(((long)NLEV * NS * (NF / 8) + 255) / 256), 256, 0, stream>>>(x, xb);

    const int gBig = 256 * (HID / 128) * NLEV;  // 4096

    // enc1: h = relu(xb @ enc_w1 + b1) -> hb
    gemm128<4, HID, 1, 0, 0><<<gBig, 256, 0, stream>>>(
        xb, NF, (long)NS * NF, nullptr,
        enc_w1t, (long)HID * NF, enc_b1, HID,
        hb, (long)NS * HID, nullptr, 0, nullptr, NF);
    // fused enc2 + vq argmin + commit
    enc2_vq<<<dim3(NS / 128, NLEV), 256, 0, stream>>>(hb, enc_w2t, enc_b2, cbb, cbn, idxp, accum);
    // dec1: h2 = relu(cb[idx] @ dec_w1 + b1d) -> hb (hb dead after enc2_vq)
    gemm128<4, HID, 1, 0, 1><<<gBig, 256, 0, stream>>>(
        cbb, 0, (long)CBS * VQD, idxp,
        dec_w1t, (long)HID * VQD, dec_b1, HID,
        hb, (long)NS * HID, nullptr, 0, nullptr, VQD);
    // dec2 + fused MSE vs bf16 x
    gemm128<4, NF, 0, 2, 0><<<gBig, 256, 0, stream>>>(
        hb, HID, (long)NS * HID, nullptr,
        dec_w2t, (long)NF * HID, dec_b2, NF,
        nullptr, 0, xb, (long)NS * NF, accum, HID);

    finalize_k<<<1, 1, 0, stream>>>(accum, (float*)d_out);
}